// Round 5
// baseline (62.118 us; speedup 1.0000x reference)
//
#include <hip/hip_runtime.h>
#include <math.h>

// DifferentiableLogicLayer:
//   out[b,g] = sum_o ops(a,b)[o] * softmax(gate_logits[g])[o]
//   a = clip(x[b, g % 8192]), b = clip(x[b, (g+1) % 8192])
// All 16 ops are affine in {1, a, b, a*b}  ==>
//   out[b,g] = c0[g] + ca[g]*a + cb[g]*b + cab[g]*a*b
//
// R4 lesson (rocprof): 1024 blocks = 16 waves/CU was latency-bound
// (Occupancy 23%, VALUBusy 11%, ~3 TB/s effective). This round: same fused
// prefetch structure, 2048 blocks = 32 waves/CU, 8 rows/thread.
// Floor: 128 MB at copy-rate ~6.3 TB/s ~= 20.3 us + ~2 us prologue.

constexpr int INPUT_SIZE = 8192;
constexpr int BATCH      = 2048;
constexpr int V4_PER_ROW = INPUT_SIZE / 4;     // 2048 float4 per row
constexpr int NBLOCKS    = 2048;               // 524288 threads -> 32 waves/CU
constexpr int ROW_STRIDE = 256;                // 524288 / 2048 col slots
constexpr int NITER      = BATCH / ROW_STRIDE; // 8 rows per thread

typedef float floatx4 __attribute__((ext_vector_type(4)));

__device__ __forceinline__ floatx4 softmax_affine(const float* __restrict__ logits, int g) {
    const floatx4* lp = reinterpret_cast<const floatx4*>(logits + (size_t)g * 16);
    floatx4 l0 = lp[0], l1 = lp[1], l2 = lp[2], l3 = lp[3];
    float p[16];
    p[0]=l0.x;  p[1]=l0.y;  p[2]=l0.z;  p[3]=l0.w;
    p[4]=l1.x;  p[5]=l1.y;  p[6]=l1.z;  p[7]=l1.w;
    p[8]=l2.x;  p[9]=l2.y;  p[10]=l2.z; p[11]=l2.w;
    p[12]=l3.x; p[13]=l3.y; p[14]=l3.z; p[15]=l3.w;

    float m = p[0];
    #pragma unroll
    for (int i = 1; i < 16; ++i) m = fmaxf(m, p[i]);
    float s = 0.f;
    #pragma unroll
    for (int i = 0; i < 16; ++i) { p[i] = __expf(p[i] - m); s += p[i]; }
    float inv = 1.f / s;

    // Coefficients of {1, a, b, ab} dotted with softmax probs:
    float c0  = p[8]+p[9]+p[10]+p[11]+p[12]+p[13]+p[14]+p[15];
    float ca  = p[2]+p[3]+p[6]+p[7] - p[8]-p[9]-p[12]-p[13];
    float cb  = p[4]+p[5]+p[6]+p[7] - p[8]-p[9]-p[10]-p[11];
    float cab = p[1]-p[2]-p[4]-2.f*p[6]-p[7]+p[8]+2.f*p[9]+p[11]+p[13]-p[14];
    floatx4 w = { c0*inv, ca*inv, cb*inv, cab*inv };
    return w;
}

__global__ __launch_bounds__(256, 8) void dll_fused_kernel(
    const float* __restrict__ x,
    const float* __restrict__ logits,
    float* __restrict__ out) {

    int tid  = blockIdx.x * blockDim.x + threadIdx.x;   // 0 .. 524287
    int col4 = tid & (V4_PER_ROW - 1);                  // fixed column slot
    int row0 = tid >> 11;                               // 0 .. 255

    int g  = col4 * 4;
    int gn = (g + 4) & (INPUT_SIZE - 1);                // wrap neighbor index

    // ---- issue 2 rows of streaming loads BEFORE the softmax prologue ----
    const float* xr0 = x + (size_t)row0 * INPUT_SIZE;
    const float* xr1 = xr0 + (size_t)ROW_STRIDE * INPUT_SIZE;
    floatx4 xv_c = *reinterpret_cast<const floatx4*>(xr0 + g);
    float   xn_c = xr0[gn];
    floatx4 xv_n = *reinterpret_cast<const floatx4*>(xr1 + g);
    float   xn_n = xr1[gn];

    // ---- prologue: this thread's 4 gate-weight vectors (hidden by loads) --
    floatx4 w0 = softmax_affine(logits, g + 0);
    floatx4 w1 = softmax_affine(logits, g + 1);
    floatx4 w2 = softmax_affine(logits, g + 2);
    floatx4 w3 = softmax_affine(logits, g + 3);

    // ---- depth-2 pipelined streaming loop (fully unrolled, NITER=8) ------
    #pragma unroll
    for (int it = 0; it < NITER; ++it) {
        int row = row0 + it * ROW_STRIDE;

        float a0 = fminf(fmaxf(xv_c.x, 0.f), 1.f);
        float a1 = fminf(fmaxf(xv_c.y, 0.f), 1.f);
        float a2 = fminf(fmaxf(xv_c.z, 0.f), 1.f);
        float a3 = fminf(fmaxf(xv_c.w, 0.f), 1.f);
        float a4 = fminf(fmaxf(xn_c,   0.f), 1.f);

        floatx4 o;
        o.x = fmaf(w0.w, a0 * a1, fmaf(w0.z, a1, fmaf(w0.y, a0, w0.x)));
        o.y = fmaf(w1.w, a1 * a2, fmaf(w1.z, a2, fmaf(w1.y, a1, w1.x)));
        o.z = fmaf(w2.w, a2 * a3, fmaf(w2.z, a3, fmaf(w2.y, a2, w2.x)));
        o.w = fmaf(w3.w, a3 * a4, fmaf(w3.z, a4, fmaf(w3.y, a3, w3.x)));

        *reinterpret_cast<floatx4*>(out + (size_t)row * INPUT_SIZE + g) = o;

        // rotate pipeline, prefetch iteration it+2 (guard folds at compile time)
        xv_c = xv_n;
        xn_c = xn_n;
        if (it + 2 < NITER) {
            const float* xr = x + (size_t)(row + 2 * ROW_STRIDE) * INPUT_SIZE;
            xv_n = *reinterpret_cast<const floatx4*>(xr + g);
            xn_n = xr[gn];
        }
    }
}

extern "C" void kernel_launch(void* const* d_in, const int* in_sizes, int n_in,
                              void* d_out, int out_size, void* d_ws, size_t ws_size,
                              hipStream_t stream) {
    const float* x      = reinterpret_cast<const float*>(d_in[0]);
    const float* logits = reinterpret_cast<const float*>(d_in[1]);
    float*       out    = reinterpret_cast<float*>(d_out);

    dll_fused_kernel<<<NBLOCKS, 256, 0, stream>>>(x, logits, out);
}

// Round 6
// 38.072 us; speedup vs baseline: 1.6316x; 1.6316x over previous
//
#include <hip/hip_runtime.h>
#include <math.h>

// DifferentiableLogicLayer:
//   out[b,g] = sum_o ops(a,b)[o] * softmax(gate_logits[g])[o]
//   a = clip(x[b, g % 8192]), b = clip(x[b, (g+1) % 8192])
// All 16 ops are affine in {1, a, b, a*b}  ==>
//   out[b,g] = c0[g] + ca[g]*a + cb[g]*b + cab[g]*a*b
//
// R5 lesson (rocprof): __launch_bounds__(256,8) capped VGPRs at 32 ->
// scratch spills on the hot path (WRITE_SIZE 64->159 MB, FETCH 34->81 MB,
// dispatch 95us). This round: IDENTICAL structure, plain __launch_bounds__(256)
// — clean A/B on the spill. 48 VGPRs already allows 8 waves/SIMD natively.
// Floor: 128 MB at copy-rate ~6.3-6.6 TB/s ~= 20 us + prologue.

constexpr int INPUT_SIZE = 8192;
constexpr int BATCH      = 2048;
constexpr int V4_PER_ROW = INPUT_SIZE / 4;     // 2048 float4 per row
constexpr int NBLOCKS    = 2048;               // 524288 threads
constexpr int ROW_STRIDE = 256;                // 524288 / 2048 col slots
constexpr int NITER      = BATCH / ROW_STRIDE; // 8 rows per thread

typedef float floatx4 __attribute__((ext_vector_type(4)));

__device__ __forceinline__ floatx4 softmax_affine(const float* __restrict__ logits, int g) {
    const floatx4* lp = reinterpret_cast<const floatx4*>(logits + (size_t)g * 16);
    floatx4 l0 = lp[0], l1 = lp[1], l2 = lp[2], l3 = lp[3];
    float p[16];
    p[0]=l0.x;  p[1]=l0.y;  p[2]=l0.z;  p[3]=l0.w;
    p[4]=l1.x;  p[5]=l1.y;  p[6]=l1.z;  p[7]=l1.w;
    p[8]=l2.x;  p[9]=l2.y;  p[10]=l2.z; p[11]=l2.w;
    p[12]=l3.x; p[13]=l3.y; p[14]=l3.z; p[15]=l3.w;

    float m = p[0];
    #pragma unroll
    for (int i = 1; i < 16; ++i) m = fmaxf(m, p[i]);
    float s = 0.f;
    #pragma unroll
    for (int i = 0; i < 16; ++i) { p[i] = __expf(p[i] - m); s += p[i]; }
    float inv = 1.f / s;

    // Coefficients of {1, a, b, ab} dotted with softmax probs:
    float c0  = p[8]+p[9]+p[10]+p[11]+p[12]+p[13]+p[14]+p[15];
    float ca  = p[2]+p[3]+p[6]+p[7] - p[8]-p[9]-p[12]-p[13];
    float cb  = p[4]+p[5]+p[6]+p[7] - p[8]-p[9]-p[10]-p[11];
    float cab = p[1]-p[2]-p[4]-2.f*p[6]-p[7]+p[8]+2.f*p[9]+p[11]+p[13]-p[14];
    floatx4 w = { c0*inv, ca*inv, cb*inv, cab*inv };
    return w;
}

__global__ __launch_bounds__(256) void dll_fused_kernel(
    const float* __restrict__ x,
    const float* __restrict__ logits,
    float* __restrict__ out) {

    int tid  = blockIdx.x * blockDim.x + threadIdx.x;   // 0 .. 524287
    int col4 = tid & (V4_PER_ROW - 1);                  // fixed column slot
    int row0 = tid >> 11;                               // 0 .. 255

    int g  = col4 * 4;
    int gn = (g + 4) & (INPUT_SIZE - 1);                // wrap neighbor index

    // ---- issue 2 rows of streaming loads BEFORE the softmax prologue ----
    const float* xr0 = x + (size_t)row0 * INPUT_SIZE;
    const float* xr1 = xr0 + (size_t)ROW_STRIDE * INPUT_SIZE;
    floatx4 xv_c = *reinterpret_cast<const floatx4*>(xr0 + g);
    float   xn_c = xr0[gn];
    floatx4 xv_n = *reinterpret_cast<const floatx4*>(xr1 + g);
    float   xn_n = xr1[gn];

    // ---- prologue: this thread's 4 gate-weight vectors (hidden by loads) --
    floatx4 w0 = softmax_affine(logits, g + 0);
    floatx4 w1 = softmax_affine(logits, g + 1);
    floatx4 w2 = softmax_affine(logits, g + 2);
    floatx4 w3 = softmax_affine(logits, g + 3);

    // ---- depth-2 pipelined streaming loop (fully unrolled, NITER=8) ------
    #pragma unroll
    for (int it = 0; it < NITER; ++it) {
        int row = row0 + it * ROW_STRIDE;

        float a0 = fminf(fmaxf(xv_c.x, 0.f), 1.f);
        float a1 = fminf(fmaxf(xv_c.y, 0.f), 1.f);
        float a2 = fminf(fmaxf(xv_c.z, 0.f), 1.f);
        float a3 = fminf(fmaxf(xv_c.w, 0.f), 1.f);
        float a4 = fminf(fmaxf(xn_c,   0.f), 1.f);

        floatx4 o;
        o.x = fmaf(w0.w, a0 * a1, fmaf(w0.z, a1, fmaf(w0.y, a0, w0.x)));
        o.y = fmaf(w1.w, a1 * a2, fmaf(w1.z, a2, fmaf(w1.y, a1, w1.x)));
        o.z = fmaf(w2.w, a2 * a3, fmaf(w2.z, a3, fmaf(w2.y, a2, w2.x)));
        o.w = fmaf(w3.w, a3 * a4, fmaf(w3.z, a4, fmaf(w3.y, a3, w3.x)));

        *reinterpret_cast<floatx4*>(out + (size_t)row * INPUT_SIZE + g) = o;

        // rotate pipeline, prefetch iteration it+2 (guard folds at compile time)
        xv_c = xv_n;
        xn_c = xn_n;
        if (it + 2 < NITER) {
            const float* xr = x + (size_t)(row + 2 * ROW_STRIDE) * INPUT_SIZE;
            xv_n = *reinterpret_cast<const floatx4*>(xr + g);
            xn_n = xr[gn];
        }
    }
}

extern "C" void kernel_launch(void* const* d_in, const int* in_sizes, int n_in,
                              void* d_out, int out_size, void* d_ws, size_t ws_size,
                              hipStream_t stream) {
    const float* x      = reinterpret_cast<const float*>(d_in[0]);
    const float* logits = reinterpret_cast<const float*>(d_in[1]);
    float*       out    = reinterpret_cast<float*>(d_out);

    dll_fused_kernel<<<NBLOCKS, 256, 0, stream>>>(x, logits, out);
}

// Round 7
// 32.226 us; speedup vs baseline: 1.9275x; 1.1814x over previous
//
#include <hip/hip_runtime.h>
#include <math.h>

// DifferentiableLogicLayer:
//   out[b,g] = sum_o ops(a,b)[o] * softmax(gate_logits[g])[o]
//   a = clip(x[b, g % 8192]), b = clip(x[b, (g+1) % 8192])
// All 16 ops are affine in {1, a, b, a*b}  ==>
//   out[b,g] = c0[g] + ca[g]*a + cb[g]*b + cab[g]*a*b
//
// Trajectory: two-kernel (R1) = 31.5us beats all fused variants (34-38us):
// the per-thread softmax prologue is redundant (256x chip-wide) and
// serializes at kernel start. So: dedupe softmax into a 128 KB w-table
// (kernel 1, trivial), stream in kernel 2.
// R7 tweaks vs R1: scalar 4B neighbor load (L1-hot) instead of 2nd float4;
// nontemporal stores so the out-stream does not evict x from L3
// (R6 counters: FETCH 34MB => x already half-L3-resident; nt stores should
// push FETCH toward 0 and the HBM floor toward ~64-70MB => ~12-15us).

constexpr int INPUT_SIZE = 8192;
constexpr int NUM_GATES  = 8192;
constexpr int BATCH      = 2048;
constexpr int V4_PER_ROW = INPUT_SIZE / 4;   // 2048 float4 per row
constexpr int NBLOCKS    = 2048;             // 524288 threads
constexpr int ROW_STRIDE = 256;              // 524288 / 2048 col slots

typedef float floatx4 __attribute__((ext_vector_type(4)));

// ---------------------------------------------------------------------------
// Kernel 1: fold softmax(gate_logits) into 4 affine coefficients per gate.
// ---------------------------------------------------------------------------
__global__ __launch_bounds__(256) void gate_weights_kernel(
    const float* __restrict__ logits, floatx4* __restrict__ w) {
    int g = blockIdx.x * blockDim.x + threadIdx.x;
    if (g >= NUM_GATES) return;

    const floatx4* lp = reinterpret_cast<const floatx4*>(logits + (size_t)g * 16);
    floatx4 l0 = lp[0], l1 = lp[1], l2 = lp[2], l3 = lp[3];
    float p[16];
    p[0]=l0.x;  p[1]=l0.y;  p[2]=l0.z;  p[3]=l0.w;
    p[4]=l1.x;  p[5]=l1.y;  p[6]=l1.z;  p[7]=l1.w;
    p[8]=l2.x;  p[9]=l2.y;  p[10]=l2.z; p[11]=l2.w;
    p[12]=l3.x; p[13]=l3.y; p[14]=l3.z; p[15]=l3.w;

    float m = p[0];
    #pragma unroll
    for (int i = 1; i < 16; ++i) m = fmaxf(m, p[i]);
    float s = 0.f;
    #pragma unroll
    for (int i = 0; i < 16; ++i) { p[i] = __expf(p[i] - m); s += p[i]; }
    float inv = 1.f / s;

    float c0  = p[8]+p[9]+p[10]+p[11]+p[12]+p[13]+p[14]+p[15];
    float ca  = p[2]+p[3]+p[6]+p[7] - p[8]-p[9]-p[12]-p[13];
    float cb  = p[4]+p[5]+p[6]+p[7] - p[8]-p[9]-p[10]-p[11];
    float cab = p[1]-p[2]-p[4]-2.f*p[6]-p[7]+p[8]+2.f*p[9]+p[11]+p[13]-p[14];
    floatx4 wv = { c0*inv, ca*inv, cb*inv, cab*inv };
    w[g] = wv;
}

// ---------------------------------------------------------------------------
// Kernel 2: streaming kernel. Each thread owns one float4 column slot,
// hoists its 4 weight vectors (L2-resident 128 KB table), walks 8 rows.
// Per row: 16B vector load + 4B scalar neighbor load (L1-hit) + 16B nt store.
// ---------------------------------------------------------------------------
__global__ __launch_bounds__(256) void dll_main_kernel(
    const float* __restrict__ x,
    const floatx4* __restrict__ w,
    float* __restrict__ out) {

    int tid  = blockIdx.x * blockDim.x + threadIdx.x;   // 0 .. 524287
    int col4 = tid & (V4_PER_ROW - 1);                  // fixed column slot
    int row0 = tid >> 11;                               // 0 .. 255

    int g  = col4 * 4;
    int gn = (g + 4) & (INPUT_SIZE - 1);                // wrap neighbor index

    floatx4 w0 = w[g + 0];
    floatx4 w1 = w[g + 1];
    floatx4 w2 = w[g + 2];
    floatx4 w3 = w[g + 3];

    for (int row = row0; row < BATCH; row += ROW_STRIDE) {
        const float* xr = x + (size_t)row * INPUT_SIZE;
        floatx4 xv = *reinterpret_cast<const floatx4*>(xr + g);
        float   xn = xr[gn];

        float a0 = fminf(fmaxf(xv.x, 0.f), 1.f);
        float a1 = fminf(fmaxf(xv.y, 0.f), 1.f);
        float a2 = fminf(fmaxf(xv.z, 0.f), 1.f);
        float a3 = fminf(fmaxf(xv.w, 0.f), 1.f);
        float a4 = fminf(fmaxf(xn,   0.f), 1.f);

        floatx4 o;
        o.x = fmaf(w0.w, a0 * a1, fmaf(w0.z, a1, fmaf(w0.y, a0, w0.x)));
        o.y = fmaf(w1.w, a1 * a2, fmaf(w1.z, a2, fmaf(w1.y, a1, w1.x)));
        o.z = fmaf(w2.w, a2 * a3, fmaf(w2.z, a3, fmaf(w2.y, a2, w2.x)));
        o.w = fmaf(w3.w, a3 * a4, fmaf(w3.z, a4, fmaf(w3.y, a3, w3.x)));

        __builtin_nontemporal_store(o,
            reinterpret_cast<floatx4*>(out + (size_t)row * INPUT_SIZE + g));
    }
}

extern "C" void kernel_launch(void* const* d_in, const int* in_sizes, int n_in,
                              void* d_out, int out_size, void* d_ws, size_t ws_size,
                              hipStream_t stream) {
    const float* x      = reinterpret_cast<const float*>(d_in[0]);
    const float* logits = reinterpret_cast<const float*>(d_in[1]);
    float*       out    = reinterpret_cast<float*>(d_out);
    floatx4*     w      = reinterpret_cast<floatx4*>(d_ws);   // 128 KB table

    gate_weights_kernel<<<NUM_GATES / 256, 256, 0, stream>>>(logits, w);
    dll_main_kernel<<<NBLOCKS, 256, 0, stream>>>(x, w, out);
}